// Round 3
// baseline (114.612 us; speedup 1.0000x reference)
//
#include <hip/hip_runtime.h>
#include <hip/hip_bf16.h>

typedef __attribute__((ext_vector_type(8))) __bf16 bf16x8;
typedef __attribute__((ext_vector_type(4))) float  f32x4;

constexpr int NROW = 8192;
constexpr int DDIM = 256;
constexpr int KDIM = 512;               // packed [x | e]
constexpr int BM = 256, BN = 256, BK = 64;
constexpr int NT = KDIM / BK;           // 8 K-tiles
constexpr int TILEBYTES = 65536;        // A(32K) + B(32K) per K-tile
constexpr int LDS_TOTAL = 2 * TILEBYTES; // 128 KB double buffer

__device__ __forceinline__ void gload_lds16(const void* g, void* l) {
  __builtin_amdgcn_global_load_lds(
      (const __attribute__((address_space(1))) void*)g,
      (__attribute__((address_space(3))) void*)l, 16, 0, 0);
}

// ---------------- prep: P = [bf16(x) | bf16(exp(1-dc))], s_i = (1-p)/d*|x_i|^2
__global__ __launch_bounds__(256) void prep_kernel(
    const float* __restrict__ x, const float* __restrict__ dc,
    const float* __restrict__ pparm,
    __hip_bfloat16* __restrict__ P, float* __restrict__ s)
{
  const int row = blockIdx.x;
  const int t   = threadIdx.x;
  const float xv = x[(size_t)row * DDIM + t];
  const float ev = __expf(1.0f - dc[(size_t)row * DDIM + t]);
  P[(size_t)row * KDIM + t]        = __float2bfloat16(xv);
  P[(size_t)row * KDIM + DDIM + t] = __float2bfloat16(ev);

  float v = xv * xv;
  #pragma unroll
  for (int off = 32; off > 0; off >>= 1) v += __shfl_down(v, off, 64);
  __shared__ float red[4];
  const int lane = t & 63, wid = t >> 6;
  if (lane == 0) red[wid] = v;
  __syncthreads();
  if (t == 0) {
    const float p = pparm[0];
    s[row] = (1.0f - p) * (1.0f / (float)DDIM) * (red[0] + red[1] + red[2] + red[3]);
  }
}

// ---------------- GEMM: G = P@P^T segment-scaled; sim = 1/(s_i+s_j+ce*G), diag=1
// m201-style 8-phase: 256x256 tile, 8 waves (2M x 4N), per-wave 128x64 out.
__global__ void __launch_bounds__(512, 2) adj_gemm(
    const __hip_bfloat16* __restrict__ P, const float* __restrict__ s,
    const float* __restrict__ pparm, float* __restrict__ out)
{
  extern __shared__ char lds[];

  const float p  = pparm[0];
  const float cx = -2.0f * (1.0f - p) / (float)DDIM;
  const float ce = p / (float)DDIM;
  const float midscale = cx / ce;

  // XCD-aware: 1024 blocks = 8 XCDs x 128; each XCD owns a 4-row-tile band.
  const int orig  = blockIdx.x;
  const int xcd   = orig & 7;
  const int local = orig >> 3;             // 0..127
  const int bi = xcd * 4 + (local & 3);    // 0..31
  const int bj = local >> 2;               // 0..31
  const int rowBase = bi * BM;
  const int colBase = bj * BN;

  const int tid  = threadIdx.x;
  const int lane = tid & 63;
  const int wid  = tid >> 6;               // 8 waves: wm = wid>>2 (2), wn = wid&3 (4)
  const int wmrow = (wid >> 2) * 128;      // wave's row base in tile
  const int wnrow = (wid & 3) * 64;        // wave's col base in tile (row of B)
  const int frow = lane & 15;
  const int kq   = lane >> 4;

  // swizzle: LDS byte (r, c) holds logical (r, c ^ ((r&7)<<4)); involution.
  const int colb0 = (kq * 16)      ^ ((frow & 7) << 4);   // ks=0 read col byte
  const int colb1 = (64 + kq * 16) ^ ((frow & 7) << 4);   // ks=1

  // staging: half-tile = 128 rows x 128 B = 16 KB, 2 loads/thread.
  const int r0   = tid >> 3;               // row within region, load j=0 (j=1: +64)
  const int cb   = (tid * 16) & 127;
  const int cbsw = cb ^ ((r0 & 7) << 4);   // (r0+64)&7 == r0&7 -> same for j=1
  const char* Pc = (const char*)P;
  const char* gA = Pc + ((size_t)(rowBase + r0) * KDIM) * 2 + cbsw;
  const char* gB = Pc + ((size_t)(colBase + r0) * KDIM) * 2 + cbsw;

  // region slot: 0=B-lo, 1=B-hi, 2=A-lo, 3=A-hi (issue order per tile)
#define STAGE(kk, region) do {                                                 \
    const char* _src = ((region) < 2 ? gB : gA) + ((region) & 1) * (128 * KDIM * 2) \
                       + (kk) * (BK * 2);                                      \
    char* _dst = lds + ((kk) & 1) * TILEBYTES                                  \
                 + (((region) < 2 ? 32768 : 0) + ((region) & 1) * 16384)       \
                 + tid * 16;                                                   \
    gload_lds16(_src, _dst);                                                   \
    gload_lds16(_src + 64 * KDIM * 2, _dst + 8192);                            \
  } while (0)

  // ---- prologue: tile0 all 4 regions, tile1 B-lo/B-hi (lead = 6 half-tiles)
  STAGE(0, 0); STAGE(0, 1); STAGE(0, 2); STAGE(0, 3);
  STAGE(1, 0); STAGE(1, 1);
  asm volatile("s_waitcnt vmcnt(4)" ::: "memory");   // tile0 landed
  asm volatile("s_barrier" ::: "memory");

  f32x4 acc[8][4];
  #pragma unroll
  for (int m = 0; m < 8; ++m)
    #pragma unroll
    for (int n = 0; n < 4; ++n)
      acc[m][n] = (f32x4){0.f, 0.f, 0.f, 0.f};

  bf16x8 a[4][2], b[4][2];

  #pragma unroll
  for (int t = 0; t < NT; ++t) {
    const char* buf  = lds + (t & 1) * TILEBYTES;
    const char* bufB = buf + 32768;

    // ---- q0: read A m-half0 (8) + B n-half0 (4); issue A-lo(t+1); MFMA 16
    #pragma unroll
    for (int i = 0; i < 4; ++i) {
      const int row = wmrow + i * 16 + frow;
      a[i][0] = *(const bf16x8*)(buf + row * 128 + colb0);
      a[i][1] = *(const bf16x8*)(buf + row * 128 + colb1);
    }
    #pragma unroll
    for (int i = 0; i < 2; ++i) {
      const int row = wnrow + i * 16 + frow;
      b[i][0] = *(const bf16x8*)(bufB + row * 128 + colb0);
      b[i][1] = *(const bf16x8*)(bufB + row * 128 + colb1);
    }
    if (t < 7) STAGE(t + 1, 2);
    asm volatile("s_barrier" ::: "memory");
    __builtin_amdgcn_s_setprio(1);
    #pragma unroll
    for (int i = 0; i < 4; ++i)
      #pragma unroll
      for (int jn = 0; jn < 2; ++jn)
        #pragma unroll
        for (int ks = 0; ks < 2; ++ks)
          acc[i][jn] = __builtin_amdgcn_mfma_f32_16x16x32_bf16(a[i][ks], b[jn][ks], acc[i][jn], 0, 0, 0);
    __builtin_amdgcn_s_setprio(0);
    asm volatile("s_barrier" ::: "memory");

    // ---- q1: read B n-half1 (4); issue A-hi(t+1); MFMA 16
    #pragma unroll
    for (int i = 0; i < 2; ++i) {
      const int row = wnrow + (2 + i) * 16 + frow;
      b[2 + i][0] = *(const bf16x8*)(bufB + row * 128 + colb0);
      b[2 + i][1] = *(const bf16x8*)(bufB + row * 128 + colb1);
    }
    if (t < 7) STAGE(t + 1, 3);
    asm volatile("s_barrier" ::: "memory");
    __builtin_amdgcn_s_setprio(1);
    #pragma unroll
    for (int i = 0; i < 4; ++i)
      #pragma unroll
      for (int jn = 0; jn < 2; ++jn)
        #pragma unroll
        for (int ks = 0; ks < 2; ++ks)
          acc[i][2 + jn] = __builtin_amdgcn_mfma_f32_16x16x32_bf16(a[i][ks], b[2 + jn][ks], acc[i][2 + jn], 0, 0, 0);
    __builtin_amdgcn_s_setprio(0);
    asm volatile("s_barrier" ::: "memory");

    // ---- q2: read A m-half1 (8); issue B-lo(t+2); MFMA 16
    #pragma unroll
    for (int i = 0; i < 4; ++i) {
      const int row = wmrow + (4 + i) * 16 + frow;
      a[i][0] = *(const bf16x8*)(buf + row * 128 + colb0);
      a[i][1] = *(const bf16x8*)(buf + row * 128 + colb1);
    }
    if (t < 6) STAGE(t + 2, 0);
    asm volatile("s_barrier" ::: "memory");
    __builtin_amdgcn_s_setprio(1);
    #pragma unroll
    for (int i = 0; i < 4; ++i)
      #pragma unroll
      for (int jn = 0; jn < 2; ++jn)
        #pragma unroll
        for (int ks = 0; ks < 2; ++ks)
          acc[4 + i][2 + jn] = __builtin_amdgcn_mfma_f32_16x16x32_bf16(a[i][ks], b[2 + jn][ks], acc[4 + i][2 + jn], 0, 0, 0);
    __builtin_amdgcn_s_setprio(0);
    asm volatile("s_barrier" ::: "memory");

    // ---- q3: no reads; issue B-hi(t+2); MFMA 16; tile-boundary vmcnt
    if (t < 6) STAGE(t + 2, 1);
    __builtin_amdgcn_s_setprio(1);
    #pragma unroll
    for (int i = 0; i < 4; ++i)
      #pragma unroll
      for (int jn = 0; jn < 2; ++jn)
        #pragma unroll
        for (int ks = 0; ks < 2; ++ks)
          acc[4 + i][jn] = __builtin_amdgcn_mfma_f32_16x16x32_bf16(a[i][ks], b[jn][ks], acc[4 + i][jn], 0, 0, 0);
    __builtin_amdgcn_s_setprio(0);

    if (t == DDIM / BK - 1) {        // x-segment done: acc = Sx -> scale by cx/ce
      #pragma unroll
      for (int m = 0; m < 8; ++m)
        #pragma unroll
        for (int n = 0; n < 4; ++n)
          acc[m][n] *= midscale;
    }

    if (t < 6)       asm volatile("s_waitcnt vmcnt(4)" ::: "memory");
    else if (t == 6) asm volatile("s_waitcnt vmcnt(0)" ::: "memory");
    if (t < 7)       asm volatile("s_barrier" ::: "memory");
  }

  // ---- epilogue: denom = s_i + s_j + ce*acc ; out = 1/denom (diag = 1)
  const int rq = lane >> 4;
  #pragma unroll
  for (int n = 0; n < 4; ++n) {
    const int gcol = colBase + wnrow + n * 16 + frow;
    const float scol = s[gcol];
    #pragma unroll
    for (int m = 0; m < 8; ++m) {
      const int growb = rowBase + wmrow + m * 16 + rq * 4;
      #pragma unroll
      for (int r = 0; r < 4; ++r) {
        const int grow = growb + r;
        const float denom = s[grow] + scol + ce * acc[m][n][r];
        const float val = (grow == gcol) ? 1.0f : __builtin_amdgcn_rcpf(denom);
        out[(size_t)grow * NROW + gcol] = val;
      }
    }
  }
}

extern "C" void kernel_launch(void* const* d_in, const int* in_sizes, int n_in,
                              void* d_out, int out_size, void* d_ws, size_t ws_size,
                              hipStream_t stream) {
  const float* x  = (const float*)d_in[0];
  const float* dc = (const float*)d_in[1];
  const float* pp = (const float*)d_in[2];
  float* out = (float*)d_out;

  __hip_bfloat16* P = (__hip_bfloat16*)d_ws;                       // 8 MB
  float* s = (float*)((char*)d_ws + (size_t)NROW * KDIM * 2);      // +32 KB

  hipFuncSetAttribute(reinterpret_cast<const void*>(adj_gemm),
                      hipFuncAttributeMaxDynamicSharedMemorySize, LDS_TOTAL);

  prep_kernel<<<NROW, 256, 0, stream>>>(x, dc, pp, P, s);
  adj_gemm<<<(NROW / BM) * (NROW / BN), 512, LDS_TOTAL, stream>>>(P, s, pp, out);
}